// Round 19
// baseline (140.242 us; speedup 1.0000x reference)
//
#include <hip/hip_runtime.h>
#include <stdint.h>

#define D_MODEL 1024
#define NHEAD 16
#define HD 64
#define BB 2
#define TT 2048
#define MR (BB*TT)   // 4096 rows

#define SCL2 0.18033688011112042f   // 0.125 * log2(e), folded into Q at projection

typedef unsigned short u16;
typedef __bf16 bf16x8 __attribute__((ext_vector_type(8)));
typedef __bf16 bf16x4v __attribute__((ext_vector_type(4)));
typedef u16 u16x8 __attribute__((ext_vector_type(8)));
typedef float f32x4 __attribute__((ext_vector_type(4)));

__device__ __forceinline__ u16 f2bf(float f) {
  union { float f; unsigned u; } v; v.f = f;
  unsigned r = v.u + 0x7FFFu + ((v.u >> 16) & 1u);
  return (u16)(r >> 16);
}

__device__ __forceinline__ void gload_lds16(const void* g, void* l) {
  __builtin_amdgcn_global_load_lds(
      (const __attribute__((address_space(1))) void*)g,
      (__attribute__((address_space(3))) void*)l, 16, 0, 0);
}

// ---------------- f32 -> bf16 convert (vectorized) ----------------
__global__ void k_f32_to_bf16(const float* __restrict__ src, u16* __restrict__ dst, int n4) {
  int idx = blockIdx.x * blockDim.x + threadIdx.x;
  int stride = gridDim.x * blockDim.x;
  for (int i = idx; i < n4; i += stride) {
    float4 v = reinterpret_cast<const float4*>(src)[i];
    ushort4 o;
    o.x = f2bf(v.x); o.y = f2bf(v.y); o.z = f2bf(v.z); o.w = f2bf(v.w);
    reinterpret_cast<ushort4*>(dst)[i] = o;
  }
}

// ---------------- transpose f32 [K][N] -> bf16 [N][K], both weights fused ----------------
__global__ void k_transpose_both(const float* __restrict__ wqkv, const float* __restrict__ wout,
                                 u16* __restrict__ dqkv, u16* __restrict__ dout) {
  __shared__ float tile[32][33];
  int bx = blockIdx.x;
  const float* src; u16* dst; int N; int n0;
  if (bx < 96) { src = wqkv; dst = dqkv; N = 3 * D_MODEL; n0 = bx * 32; }
  else         { src = wout; dst = dout; N = D_MODEL;     n0 = (bx - 96) * 32; }
  const int K = D_MODEL;
  int k0 = blockIdx.y * 32;
  int tx = threadIdx.x, ty = threadIdx.y;  // block (32,8)
  #pragma unroll
  for (int i = 0; i < 32; i += 8)
    tile[ty + i][tx] = src[(size_t)(k0 + ty + i) * N + n0 + tx];
  __syncthreads();
  #pragma unroll
  for (int i = 0; i < 32; i += 8)
    dst[(size_t)(n0 + ty + i) * K + k0 + tx] = f2bf(tile[tx][ty + i]);
}

// ---------------- bf16 GEMM, B^T input, 128x64 tile, swizzled + pipelined (R18) ----------------
template<int MODE>
__global__ __launch_bounds__(256)
void k_gemm_bt(const u16* __restrict__ A, const u16* __restrict__ Bt,
               const float* __restrict__ bias,
               u16* __restrict__ q_out, u16* __restrict__ k_out, u16* __restrict__ v_out,
               float* __restrict__ c_out, int M, int N, int K)
{
  __shared__ __align__(16) u16 a_sh[2][128 * 64];
  __shared__ __align__(16) u16 b_sh[2][64 * 64];
  const int u = threadIdx.x;
  const int lane = u & 63;
  const int w = u >> 6;           // wave = row quadrant (32 rows)
  const int m0 = blockIdx.y * 128;
  const int n0 = blockIdx.x * 64;
  const int r = lane & 15, q4 = lane >> 4;

  f32x4 acc[2][4];
  #pragma unroll
  for (int i = 0; i < 2; i++)
    #pragma unroll
    for (int j = 0; j < 4; j++) acc[i][j] = {0.f, 0.f, 0.f, 0.f};

  const int arow = u >> 3;                          // 0..31
  const int acol = ((u & 7) ^ ((u >> 3) & 7)) * 8;  // inverse-swizzled source slot
  const u16* Ag = A + (size_t)(m0 + arow) * K + acol;
  const u16* Bg = Bt + (size_t)(n0 + arow) * K + acol;

  const int fs0 = ((0 * 4 + q4) ^ (r & 7)) * 8;
  const int fs1 = ((1 * 4 + q4) ^ (r & 7)) * 8;

  const int NK = K >> 6;

  #pragma unroll
  for (int i = 0; i < 4; i++)
    gload_lds16(Ag + (size_t)i * 32 * K, &a_sh[0][(i * 32 + w * 8) * 64]);
  #pragma unroll
  for (int i = 0; i < 2; i++)
    gload_lds16(Bg + (size_t)i * 32 * K, &b_sh[0][(i * 32 + w * 8) * 64]);
  __syncthreads();

  for (int kk = 0; kk < NK; kk++) {
    const int cur = kk & 1;
    if (kk + 1 < NK) {
      const int k0 = (kk + 1) << 6;
      #pragma unroll
      for (int i = 0; i < 4; i++)
        gload_lds16(Ag + (size_t)i * 32 * K + k0, &a_sh[cur ^ 1][(i * 32 + w * 8) * 64]);
      #pragma unroll
      for (int i = 0; i < 2; i++)
        gload_lds16(Bg + (size_t)i * 32 * K + k0, &b_sh[cur ^ 1][(i * 32 + w * 8) * 64]);
    }
    #pragma unroll
    for (int kc = 0; kc < 2; kc++) {
      const int fs = kc ? fs1 : fs0;
      bf16x8 af[2], bfr[4];
      #pragma unroll
      for (int m = 0; m < 2; m++)
        af[m] = *reinterpret_cast<const bf16x8*>(&a_sh[cur][(w * 32 + m * 16 + r) * 64 + fs]);
      #pragma unroll
      for (int n = 0; n < 4; n++)
        bfr[n] = *reinterpret_cast<const bf16x8*>(&b_sh[cur][(n * 16 + r) * 64 + fs]);
      #pragma unroll
      for (int m = 0; m < 2; m++)
        #pragma unroll
        for (int n = 0; n < 4; n++)
          acc[m][n] = __builtin_amdgcn_mfma_f32_16x16x32_bf16(af[m], bfr[n], acc[m][n], 0, 0, 0);
    }
    __syncthreads();
  }

  if (MODE == 0) {
    #pragma unroll
    for (int n = 0; n < 4; n++) {
      int gcol = n0 + n * 16 + r;
      int which = gcol >> 10;
      int rem = gcol & 1023;
      int h = rem >> 6, d = rem & 63;
      float bv = bias[gcol];
      #pragma unroll
      for (int m = 0; m < 2; m++) {
        #pragma unroll
        for (int reg = 0; reg < 4; reg++) {
          int grow = m0 + w * 32 + m * 16 + q4 * 4 + reg;
          int b = grow >> 11, t = grow & 2047;
          float fv = acc[m][n][reg] + bv;
          if (which == 0)
            q_out[(((size_t)(b * NHEAD + h) * TT + t) << 6) + d] = f2bf(fv * SCL2);
          else if (which == 1)
            k_out[(((size_t)(b * NHEAD + h) * TT + t) << 6) + d] = f2bf(fv);
          else  // V transposed: [b][h][d][t]
            v_out[(((size_t)(b * NHEAD + h) * HD + d) * TT) + t] = f2bf(fv);
        }
      }
    }
  } else {
    #pragma unroll
    for (int m = 0; m < 2; m++) {
      #pragma unroll
      for (int reg = 0; reg < 4; reg++) {
        int grow = m0 + w * 32 + m * 16 + q4 * 4 + reg;
        #pragma unroll
        for (int n = 0; n < 4; n++) {
          int gcol = n0 + n * 16 + r;
          c_out[(size_t)grow * N + gcol] = acc[m][n][reg] + bias[gcol];
        }
      }
    }
  }
}

// ---------------- causal flash attention: pipelined K-LDS, direct-V ----------------
// R16 structure (128-row supertile, 4 subtiles x 2 k-halves, complementary CU
// pairing) with the barrier diet: K tiles time-double-buffered in shared LDS
// (stage i+1 FIRST, compute i, ONE __syncthreads per iter -> stage latency
// hides under compute); V fragments loaded per-wave direct from global
// (issued after QK, latency hides under softmax; frees 16KB so dbuf fits in
// the same 69632B -> still 2 blocks/CU).
#define DEFER_THR 6.0f

__device__ __forceinline__ void attn_step(
    const u16* __restrict__ kb, const u16* __restrict__ Vp, int kt,
    const bf16x8 (&qf)[2][2], f32x4 (&of)[2][4],
    float (&m_run)[2], float (&lp)[2],
    u16* pw, bool diag, int q0, int r, int q4, int fsw0, int fsw1)
{
  // S^T = mfma(K, Q): K A-fragments from swizzled shared LDS
  f32x4 sf[2][4];
  __builtin_amdgcn_s_setprio(1);
  #pragma unroll
  for (int n = 0; n < 4; n++) {
    bf16x8 k0f = *reinterpret_cast<const bf16x8*>(&kb[(n * 16 + r) * 64 + fsw0]);
    bf16x8 k1f = *reinterpret_cast<const bf16x8*>(&kb[(n * 16 + r) * 64 + fsw1]);
    #pragma unroll
    for (int g = 0; g < 2; g++) {
      f32x4 a = {0.f, 0.f, 0.f, 0.f};
      a = __builtin_amdgcn_mfma_f32_16x16x32_bf16(k0f, qf[g][0], a, 0, 0, 0);
      a = __builtin_amdgcn_mfma_f32_16x16x32_bf16(k1f, qf[g][1], a, 0, 0, 0);
      sf[g][n] = a;
    }
  }
  __builtin_amdgcn_s_setprio(0);

  // V fragments direct from global (R14 addressing); latency hides under softmax
  bf16x8 vf[2][4];
  #pragma unroll
  for (int d0 = 0; d0 < 4; d0++) {
    const u16* vp = Vp + (size_t)d0 * (16 * TT) + kt * 64;
    vf[0][d0] = *reinterpret_cast<const bf16x8*>(vp);
    vf[1][d0] = *reinterpret_cast<const bf16x8*>(vp + 32);
  }

  #pragma unroll
  for (int g = 0; g < 2; g++) {
    const int myq = q0 + g * 16 + r;
    if (diag) {
      #pragma unroll
      for (int n = 0; n < 4; n++)
        #pragma unroll
        for (int reg = 0; reg < 4; reg++) {
          int kg = kt * 64 + n * 16 + q4 * 4 + reg;
          if (kg > myq) sf[g][n][reg] = -1e30f;
        }
    }
    float ma = fmaxf(fmaxf(sf[g][0][0], sf[g][0][1]), sf[g][0][2]);
    float mb = fmaxf(fmaxf(sf[g][0][3], sf[g][1][0]), sf[g][1][1]);
    float mc = fmaxf(fmaxf(sf[g][1][2], sf[g][1][3]), sf[g][2][0]);
    float md = fmaxf(fmaxf(sf[g][2][1], sf[g][2][2]), sf[g][2][3]);
    float me = fmaxf(fmaxf(sf[g][3][0], sf[g][3][1]), sf[g][3][2]);
    float mt = fmaxf(fmaxf(fmaxf(ma, mb), fmaxf(mc, md)), fmaxf(me, sf[g][3][3]));

    if (!__all(mt <= m_run[g] + DEFER_THR)) {
      float fm = fmaxf(mt, __shfl_xor(mt, 16));
      fm = fmaxf(fm, __shfl_xor(fm, 32));
      float mnew = fmaxf(m_run[g], fm);
      float alpha = __builtin_amdgcn_exp2f(m_run[g] - mnew);
      lp[g] *= alpha;
      #pragma unroll
      for (int d0 = 0; d0 < 4; d0++)
        of[g][d0] *= alpha;
      m_run[g] = mnew;
    }

    f32x4 ss = {0.f, 0.f, 0.f, 0.f};
    #pragma unroll
    for (int n = 0; n < 4; n++) {
      #pragma unroll
      for (int reg = 0; reg < 4; reg++)
        sf[g][n][reg] = __builtin_amdgcn_exp2f(sf[g][n][reg] - m_run[g]);
      ss += sf[g][n];
    }
    lp[g] += (ss[0] + ss[1]) + (ss[2] + ss[3]);

    #pragma unroll
    for (int n = 0; n < 4; n++) {
      bf16x4v pv;
      pv[0] = (__bf16)sf[g][n][0]; pv[1] = (__bf16)sf[g][n][1];
      pv[2] = (__bf16)sf[g][n][2]; pv[3] = (__bf16)sf[g][n][3];
      *reinterpret_cast<bf16x4v*>(&pw[(g * 16 + r) * 72 + n * 16 + q4 * 4]) = pv;
    }
  }

  // O^T += mfma(V, P)
  #pragma unroll
  for (int g = 0; g < 2; g++)
    #pragma unroll
    for (int kc = 0; kc < 2; kc++) {
      bf16x8 pa = *reinterpret_cast<const bf16x8*>(&pw[(g * 16 + r) * 72 + kc * 32 + q4 * 8]);
      #pragma unroll
      for (int d0 = 0; d0 < 4; d0++)
        of[g][d0] = __builtin_amdgcn_mfma_f32_16x16x32_bf16(vf[kc][d0], pa, of[g][d0], 0, 0, 0);
    }
}

__global__ __launch_bounds__(512)
void k_attn(const u16* __restrict__ Q, const u16* __restrict__ Kk,
            const u16* __restrict__ Vt, u16* __restrict__ Y)
{
  __shared__ __align__(16) u16 kbuf[2][2][64 * 64];  // [time][half]: 32 KB
  __shared__ __align__(16) u16 p_sh[8][32 * 72];     // 36.9 KB; overlaid by merge

  const int u = threadIdx.x;
  const int lane = u & 63;
  const int w = u >> 6;                 // 0..7
  const int r = lane & 15, q4 = lane >> 4;
  const int xcd = blockIdx.x & 7;
  const int j = blockIdx.x >> 3;        // 0..63
  const int p = j & 31;
  const int member = j >> 5;            // 0: long supertiles (8..15), 1: short (0..7)
  const int bh = xcd * 4 + (p & 3);
  const int st = member ? (p >> 2) : (15 - (p >> 2));   // 128-row supertile 0..15
  const int s = w & 3;                  // subtile (32 rows)
  const int hf = w >> 2;                // k-half
  const int b = bh >> 4, h = bh & 15;
  const size_t head_off = (size_t)bh * TT * HD;   // Q,K: [t][d]; Vt: [d][t]
  const int q0 = st * 128 + s * 32;     // this wave's 32 q-rows
  const int NTh = st + 1;               // tiles per half (NT = 2*NTh)
  const int ktmax = q0 >> 6;            // = 2*st + (s>>1)

  // staging: wave w stages rows [w*8, w*8+8) of each half's tile, swizzled source
  const int srow = w * 8 + (lane >> 3);
  const int sg = (lane & 7) ^ (srow & 7);
  const u16* Ksrc = Kk + head_off + (size_t)srow * HD + sg * 8;   // + kt*64*HD
  const u16* Vp = Vt + head_off + (size_t)r * TT + q4 * 8;        // per-lane V base

  bf16x8 qf[2][2];
  #pragma unroll
  for (int g = 0; g < 2; g++) {
    const u16* qp = &Q[head_off + (size_t)(q0 + g * 16 + r) * HD + q4 * 8];
    qf[g][0] = *reinterpret_cast<const bf16x8*>(qp);
    qf[g][1] = *reinterpret_cast<const bf16x8*>(qp + 32);
  }

  f32x4 of[2][4];
  #pragma unroll
  for (int g = 0; g < 2; g++)
    #pragma unroll
    for (int k = 0; k < 4; k++) of[g][k] = {0.f, 0.f, 0.f, 0.f};
  float m_run[2] = {-1e30f, -1e30f};
  float lp[2] = {0.f, 0.f};

  u16* pw = &p_sh[w][0];
  const int fsw0 = ((0 * 4 + q4) ^ (r & 7)) * 8;
  const int fsw1 = ((1 * 4 + q4) ^ (r & 7)) * 8;

  // prologue: stage both halves' tile 0 (kt=0 and kt=NTh) into time-buffer 0
  gload_lds16(Ksrc,                              &kbuf[0][0][w * 512]);
  gload_lds16(Ksrc + (size_t)NTh * (64 * HD),    &kbuf[0][1][w * 512]);
  __syncthreads();

  for (int i = 0; i < NTh; i++) {
    const int tb = i & 1;
    // issue next iteration's K staging FIRST (latency hides under compute)
    if (i + 1 < NTh) {
      gload_lds16(Ksrc + (size_t)(i + 1) * (64 * HD),        &kbuf[tb ^ 1][0][w * 512]);
      gload_lds16(Ksrc + (size_t)(i + 1 + NTh) * (64 * HD),  &kbuf[tb ^ 1][1][w * 512]);
    }
    const int kt = i + hf * NTh;
    if (kt <= ktmax)
      attn_step(&kbuf[tb][hf][0], Vp, kt, qf, of, m_run, lp, pw,
                kt == ktmax, q0, r, q4, fsw0, fsw1);
    __syncthreads();   // drains next-tile staging + buffer hand-off
  }

  // ---- in-LDS merge of the two k-halves per subtile (overlaid on p_sh) ----
  float* msh = reinterpret_cast<float*>(&p_sh[0][0]);   // 4 slots x 36x64 f32
  if (hf == 1) {
    float* mb = msh + (s * 36) * 64 + lane;
    #pragma unroll
    for (int g = 0; g < 2; g++) {
      #pragma unroll
      for (int d0 = 0; d0 < 4; d0++)
        #pragma unroll
        for (int jj = 0; jj < 4; jj++)
          mb[(g * 16 + d0 * 4 + jj) * 64] = of[g][d0][jj];
      mb[(32 + g) * 64] = m_run[g];
      mb[(34 + g) * 64] = lp[g];
    }
  }
  __syncthreads();
  if (hf == 0) {
    const float* mb = msh + (s * 36) * 64 + lane;
    #pragma unroll
    for (int g = 0; g < 2; g++) {
      float m1 = mb[(32 + g) * 64];
      float l1 = mb[(34 + g) * 64];
      float M = fmaxf(m_run[g], m1);
      float a0 = __builtin_amdgcn_exp2f(m_run[g] - M);
      float a1 = __builtin_amdgcn_exp2f(m1 - M);
      float lc = lp[g] * a0 + l1 * a1;
      lc += __shfl_xor(lc, 16);
      lc += __shfl_xor(lc, 32);
      float inv = 1.0f / lc;
      const int t = q0 + g * 16 + r;
      #pragma unroll
      for (int d0 = 0; d0 < 4; d0++) {
        f32x4 oc;
        #pragma unroll
        for (int jj = 0; jj < 4; jj++)
          oc[jj] = of[g][d0][jj] * a0 + mb[(g * 16 + d0 * 4 + jj) * 64] * a1;
        bf16x4v yv;
        yv[0] = (__bf16)(oc[0] * inv); yv[1] = (__bf16)(oc[1] * inv);
        yv[2] = (__bf16)(oc[2] * inv); yv[3] = (__bf16)(oc[3] * inv);
        *reinterpret_cast<bf16x4v*>(&Y[((size_t)(b * TT + t) << 10) + h * 64 + d0 * 16 + q4 * 4]) = yv;
      }
    }
  }
}

// ---------------- host launcher ----------------
extern "C" void kernel_launch(void* const* d_in, const int* in_sizes, int n_in,
                              void* d_out, int out_size, void* d_ws, size_t ws_size,
                              hipStream_t stream) {
  const float* x     = (const float*)d_in[0];
  const float* w_qkv = (const float*)d_in[1];
  const float* b_qkv = (const float*)d_in[2];
  const float* w_out = (const float*)d_in[3];
  const float* b_out = (const float*)d_in[4];
  float* out = (float*)d_out;

  uint8_t* ws = (uint8_t*)d_ws;
  u16* xb    = (u16*)(ws);                    // 8 MB  (reused as y_heads later)
  u16* wqkvT = (u16*)(ws + (8u  << 20));      // 6 MB
  u16* woutT = (u16*)(ws + (14u << 20));      // 2 MB
  u16* Qh    = (u16*)(ws + (16u << 20));      // 8 MB
  u16* Kh    = (u16*)(ws + (24u << 20));      // 8 MB
  u16* Vth   = (u16*)(ws + (32u << 20));      // 8 MB  (transposed V)

  k_f32_to_bf16<<<1024, 256, 0, stream>>>(x, xb, (MR * D_MODEL) / 4);
  k_transpose_both<<<dim3(128, D_MODEL / 32), dim3(32, 8), 0, stream>>>(
      w_qkv, w_out, wqkvT, woutT);

  k_gemm_bt<0><<<dim3(3 * D_MODEL / 64, MR / 128), 256, 0, stream>>>(
      xb, wqkvT, b_qkv, Qh, Kh, Vth, nullptr, MR, 3 * D_MODEL, D_MODEL);

  u16* Yh = xb;  // reuse x-bf16 region
  k_attn<<<dim3(512), dim3(512), 0, stream>>>(Qh, Kh, Vth, Yh);

  k_gemm_bt<1><<<dim3(D_MODEL / 64, MR / 128), 256, 0, stream>>>(
      Yh, woutT, b_out, nullptr, nullptr, nullptr, out, MR, D_MODEL, D_MODEL);
}

// Round 20
// 123.169 us; speedup vs baseline: 1.1386x; 1.1386x over previous
//
#include <hip/hip_runtime.h>
#include <stdint.h>

#define D_MODEL 1024
#define NHEAD 16
#define HD 64
#define BB 2
#define TT 2048
#define MR (BB*TT)   // 4096 rows

#define SCL2 0.18033688011112042f   // 0.125 * log2(e), folded into Q at projection

typedef unsigned short u16;
typedef __bf16 bf16x8 __attribute__((ext_vector_type(8)));
typedef __bf16 bf16x4v __attribute__((ext_vector_type(4)));
typedef u16 u16x8 __attribute__((ext_vector_type(8)));
typedef float f32x4 __attribute__((ext_vector_type(4)));

__device__ __forceinline__ u16 f2bf(float f) {
  union { float f; unsigned u; } v; v.f = f;
  unsigned r = v.u + 0x7FFFu + ((v.u >> 16) & 1u);
  return (u16)(r >> 16);
}

__device__ __forceinline__ void gload_lds16(const void* g, void* l) {
  __builtin_amdgcn_global_load_lds(
      (const __attribute__((address_space(1))) void*)g,
      (__attribute__((address_space(3))) void*)l, 16, 0, 0);
}

// ---------------- f32 -> bf16 convert (vectorized) ----------------
__global__ void k_f32_to_bf16(const float* __restrict__ src, u16* __restrict__ dst, int n4) {
  int idx = blockIdx.x * blockDim.x + threadIdx.x;
  int stride = gridDim.x * blockDim.x;
  for (int i = idx; i < n4; i += stride) {
    float4 v = reinterpret_cast<const float4*>(src)[i];
    ushort4 o;
    o.x = f2bf(v.x); o.y = f2bf(v.y); o.z = f2bf(v.z); o.w = f2bf(v.w);
    reinterpret_cast<ushort4*>(dst)[i] = o;
  }
}

// ---------------- transpose f32 [K][N] -> bf16 [N][K], both weights fused ----------------
__global__ void k_transpose_both(const float* __restrict__ wqkv, const float* __restrict__ wout,
                                 u16* __restrict__ dqkv, u16* __restrict__ dout) {
  __shared__ float tile[32][33];
  int bx = blockIdx.x;
  const float* src; u16* dst; int N; int n0;
  if (bx < 96) { src = wqkv; dst = dqkv; N = 3 * D_MODEL; n0 = bx * 32; }
  else         { src = wout; dst = dout; N = D_MODEL;     n0 = (bx - 96) * 32; }
  const int K = D_MODEL;
  int k0 = blockIdx.y * 32;
  int tx = threadIdx.x, ty = threadIdx.y;  // block (32,8)
  #pragma unroll
  for (int i = 0; i < 32; i += 8)
    tile[ty + i][tx] = src[(size_t)(k0 + ty + i) * N + n0 + tx];
  __syncthreads();
  #pragma unroll
  for (int i = 0; i < 32; i += 8)
    dst[(size_t)(n0 + ty + i) * K + k0 + tx] = f2bf(tile[tx][ty + i]);
}

// ---------------- bf16 GEMM, B^T input, 128x128 tile, swizzled (R17 structure) ----------------
// Conflicts eliminated by R17's swizzle -> revisit the bigger tile: 32 KB staged
// per 128 MFMAs (1.5x better MFMA:byte ratio than 128x64). 4 waves, each owns a
// 64x64 quadrant (4x4 frags). Grid: MODE0 24x32=768 (3/CU), MODE1 8x32=256.
// Single-buffered, 2 barriers/k-step (R18 dbuf was neutral); rule #21 swizzle.
template<int MODE>
__global__ __launch_bounds__(256)
void k_gemm_bt(const u16* __restrict__ A, const u16* __restrict__ Bt,
               const float* __restrict__ bias,
               u16* __restrict__ q_out, u16* __restrict__ k_out, u16* __restrict__ v_out,
               float* __restrict__ c_out, int M, int N, int K)
{
  __shared__ __align__(16) u16 a_sh[128 * 64];
  __shared__ __align__(16) u16 b_sh[128 * 64];
  const int u = threadIdx.x;
  const int lane = u & 63;
  const int w = u >> 6;
  const int wr = w >> 1, wc = w & 1;    // 2x2 wave grid, 64x64 quadrant each
  const int m0 = blockIdx.y * 128;
  const int n0 = blockIdx.x * 128;
  const int r = lane & 15, q4 = lane >> 4;

  f32x4 acc[4][4];
  #pragma unroll
  for (int i = 0; i < 4; i++)
    #pragma unroll
    for (int j = 0; j < 4; j++) acc[i][j] = {0.f, 0.f, 0.f, 0.f};

  const int arow = u >> 3;                          // 0..31
  const int acol = ((u & 7) ^ ((u >> 3) & 7)) * 8;  // inverse-swizzled source slot
  const u16* Ag = A + (size_t)(m0 + arow) * K + acol;
  const u16* Bg = Bt + (size_t)(n0 + arow) * K + acol;

  // swizzled fragment-read slot offsets (u16 elems): ((kc*4+q4)^(r&7))*8
  const int fs0 = ((0 * 4 + q4) ^ (r & 7)) * 8;
  const int fs1 = ((1 * 4 + q4) ^ (r & 7)) * 8;

  for (int k0 = 0; k0 < K; k0 += 64) {
    #pragma unroll
    for (int i = 0; i < 4; i++) {
      gload_lds16(Ag + (size_t)i * 32 * K + k0, &a_sh[(i * 32 + w * 8) * 64]);
      gload_lds16(Bg + (size_t)i * 32 * K + k0, &b_sh[(i * 32 + w * 8) * 64]);
    }
    __syncthreads();
    #pragma unroll
    for (int kc = 0; kc < 2; kc++) {
      const int fs = kc ? fs1 : fs0;
      bf16x8 af[4], bfr[4];
      #pragma unroll
      for (int m = 0; m < 4; m++)
        af[m] = *reinterpret_cast<const bf16x8*>(&a_sh[(wr * 64 + m * 16 + r) * 64 + fs]);
      #pragma unroll
      for (int n = 0; n < 4; n++)
        bfr[n] = *reinterpret_cast<const bf16x8*>(&b_sh[(wc * 64 + n * 16 + r) * 64 + fs]);
      #pragma unroll
      for (int m = 0; m < 4; m++)
        #pragma unroll
        for (int n = 0; n < 4; n++)
          acc[m][n] = __builtin_amdgcn_mfma_f32_16x16x32_bf16(af[m], bfr[n], acc[m][n], 0, 0, 0);
    }
    __syncthreads();
  }

  if (MODE == 0) {
    #pragma unroll
    for (int n = 0; n < 4; n++) {
      int gcol = n0 + wc * 64 + n * 16 + r;
      int which = gcol >> 10;   // uniform within fragment (16-aligned ranges)
      int rem = gcol & 1023;
      int h = rem >> 6, d = rem & 63;
      float bv = bias[gcol];
      #pragma unroll
      for (int m = 0; m < 4; m++) {
        #pragma unroll
        for (int reg = 0; reg < 4; reg++) {
          int grow = m0 + wr * 64 + m * 16 + q4 * 4 + reg;
          int b = grow >> 11, t = grow & 2047;
          float fv = acc[m][n][reg] + bv;
          if (which == 0)
            q_out[(((size_t)(b * NHEAD + h) * TT + t) << 6) + d] = f2bf(fv * SCL2);
          else if (which == 1)
            k_out[(((size_t)(b * NHEAD + h) * TT + t) << 6) + d] = f2bf(fv);
          else  // V transposed: [b][h][d][t]
            v_out[(((size_t)(b * NHEAD + h) * HD + d) * TT) + t] = f2bf(fv);
        }
      }
    }
  } else {
    #pragma unroll
    for (int m = 0; m < 4; m++) {
      #pragma unroll
      for (int reg = 0; reg < 4; reg++) {
        int grow = m0 + wr * 64 + m * 16 + q4 * 4 + reg;
        #pragma unroll
        for (int n = 0; n < 4; n++) {
          int gcol = n0 + wc * 64 + n * 16 + r;
          c_out[(size_t)grow * N + gcol] = acc[m][n][reg] + bias[gcol];
        }
      }
    }
  }
}

// ---------------- causal flash attention (R16/R17/R18 proven version, unchanged) ----------------
#define DEFER_THR 6.0f

__device__ __forceinline__ void attn_step(
    const u16* __restrict__ kb, const u16* __restrict__ vb,
    const bf16x8 (&qf)[2][2], f32x4 (&of)[2][4],
    float (&m_run)[2], float (&lp)[2],
    u16* pw, int kt, bool diag, int q0, int r, int q4, int fsw0, int fsw1)
{
  // S^T = mfma(K, Q): K A-fragments from swizzled LDS
  f32x4 sf[2][4];
  __builtin_amdgcn_s_setprio(1);
  #pragma unroll
  for (int n = 0; n < 4; n++) {
    bf16x8 k0f = *reinterpret_cast<const bf16x8*>(&kb[(n * 16 + r) * 64 + fsw0]);
    bf16x8 k1f = *reinterpret_cast<const bf16x8*>(&kb[(n * 16 + r) * 64 + fsw1]);
    #pragma unroll
    for (int g = 0; g < 2; g++) {
      f32x4 a = {0.f, 0.f, 0.f, 0.f};
      a = __builtin_amdgcn_mfma_f32_16x16x32_bf16(k0f, qf[g][0], a, 0, 0, 0);
      a = __builtin_amdgcn_mfma_f32_16x16x32_bf16(k1f, qf[g][1], a, 0, 0, 0);
      sf[g][n] = a;
    }
  }
  __builtin_amdgcn_s_setprio(0);

  // V A-fragments from swizzled LDS
  bf16x8 vf[2][4];
  #pragma unroll
  for (int d0 = 0; d0 < 4; d0++) {
    vf[0][d0] = *reinterpret_cast<const bf16x8*>(&vb[(d0 * 16 + r) * 64 + fsw0]);
    vf[1][d0] = *reinterpret_cast<const bf16x8*>(&vb[(d0 * 16 + r) * 64 + fsw1]);
  }

  #pragma unroll
  for (int g = 0; g < 2; g++) {
    const int myq = q0 + g * 16 + r;
    if (diag) {
      #pragma unroll
      for (int n = 0; n < 4; n++)
        #pragma unroll
        for (int reg = 0; reg < 4; reg++) {
          int kg = kt * 64 + n * 16 + q4 * 4 + reg;
          if (kg > myq) sf[g][n][reg] = -1e30f;
        }
    }
    float ma = fmaxf(fmaxf(sf[g][0][0], sf[g][0][1]), sf[g][0][2]);
    float mb = fmaxf(fmaxf(sf[g][0][3], sf[g][1][0]), sf[g][1][1]);
    float mc = fmaxf(fmaxf(sf[g][1][2], sf[g][1][3]), sf[g][2][0]);
    float md = fmaxf(fmaxf(sf[g][2][1], sf[g][2][2]), sf[g][2][3]);
    float me = fmaxf(fmaxf(sf[g][3][0], sf[g][3][1]), sf[g][3][2]);
    float mt = fmaxf(fmaxf(fmaxf(ma, mb), fmaxf(mc, md)), fmaxf(me, sf[g][3][3]));

    if (!__all(mt <= m_run[g] + DEFER_THR)) {
      float fm = fmaxf(mt, __shfl_xor(mt, 16));
      fm = fmaxf(fm, __shfl_xor(fm, 32));
      float mnew = fmaxf(m_run[g], fm);
      float alpha = __builtin_amdgcn_exp2f(m_run[g] - mnew);
      lp[g] *= alpha;
      #pragma unroll
      for (int d0 = 0; d0 < 4; d0++)
        of[g][d0] *= alpha;
      m_run[g] = mnew;
    }

    f32x4 ss = {0.f, 0.f, 0.f, 0.f};
    #pragma unroll
    for (int n = 0; n < 4; n++) {
      #pragma unroll
      for (int reg = 0; reg < 4; reg++)
        sf[g][n][reg] = __builtin_amdgcn_exp2f(sf[g][n][reg] - m_run[g]);
      ss += sf[g][n];
    }
    lp[g] += (ss[0] + ss[1]) + (ss[2] + ss[3]);

    #pragma unroll
    for (int n = 0; n < 4; n++) {
      bf16x4v pv;
      pv[0] = (__bf16)sf[g][n][0]; pv[1] = (__bf16)sf[g][n][1];
      pv[2] = (__bf16)sf[g][n][2]; pv[3] = (__bf16)sf[g][n][3];
      *reinterpret_cast<bf16x4v*>(&pw[(g * 16 + r) * 72 + n * 16 + q4 * 4]) = pv;
    }
  }

  // O^T += mfma(V, P)
  #pragma unroll
  for (int g = 0; g < 2; g++)
    #pragma unroll
    for (int kc = 0; kc < 2; kc++) {
      bf16x8 pa = *reinterpret_cast<const bf16x8*>(&pw[(g * 16 + r) * 72 + kc * 32 + q4 * 8]);
      #pragma unroll
      for (int d0 = 0; d0 < 4; d0++)
        of[g][d0] = __builtin_amdgcn_mfma_f32_16x16x32_bf16(vf[kc][d0], pa, of[g][d0], 0, 0, 0);
    }
}

__global__ __launch_bounds__(512)
void k_attn(const u16* __restrict__ Q, const u16* __restrict__ Kk,
            const u16* __restrict__ Vt, u16* __restrict__ Y)
{
  __shared__ __align__(16) u16 kbuf[2][64 * 64];   // slot hf: 16 KB total
  __shared__ __align__(16) u16 vbuf[2][64 * 64];   // 16 KB
  __shared__ __align__(16) u16 p_sh[8][32 * 72];   // 36.9 KB; overlaid by merge (4 x 36x64 f32)

  const int u = threadIdx.x;
  const int lane = u & 63;
  const int w = u >> 6;                 // 0..7
  const int r = lane & 15, q4 = lane >> 4;
  const int xcd = blockIdx.x & 7;
  const int j = blockIdx.x >> 3;        // 0..63
  const int p = j & 31;
  const int member = j >> 5;            // 0: long supertiles (8..15), 1: short (0..7)
  const int bh = xcd * 4 + (p & 3);
  const int st = member ? (p >> 2) : (15 - (p >> 2));   // 128-row supertile 0..15
  const int s = w & 3;                  // subtile (32 rows)
  const int hf = w >> 2;                // k-half
  const int b = bh >> 4, h = bh & 15;
  const size_t head_off = (size_t)bh * TT * HD;   // Q,K: [t][d]; Vt: [d][t]
  const int q0 = st * 128 + s * 32;     // this wave's 32 q-rows
  const int NTh = st + 1;               // tiles per half (NT = 2*NTh)
  const int ktmax = q0 >> 6;            // = 2*st + (s>>1)

  // staging: wave w stages rows [w*8, w*8+8) of each tile, swizzled source
  const int srow = w * 8 + (lane >> 3);
  const int sg = (lane & 7) ^ (srow & 7);
  const u16* Ksrc = Kk + head_off + (size_t)srow * HD + sg * 8;   // + kt*64*HD
  const u16* Vsrc = Vt + head_off + (size_t)srow * TT + sg * 8;   // + kt*64

  bf16x8 qf[2][2];
  #pragma unroll
  for (int g = 0; g < 2; g++) {
    const u16* qp = &Q[head_off + (size_t)(q0 + g * 16 + r) * HD + q4 * 8];
    qf[g][0] = *reinterpret_cast<const bf16x8*>(qp);
    qf[g][1] = *reinterpret_cast<const bf16x8*>(qp + 32);
  }

  f32x4 of[2][4];
  #pragma unroll
  for (int g = 0; g < 2; g++)
    #pragma unroll
    for (int k = 0; k < 4; k++) of[g][k] = {0.f, 0.f, 0.f, 0.f};
  float m_run[2] = {-1e30f, -1e30f};
  float lp[2] = {0.f, 0.f};

  u16* pw = &p_sh[w][0];
  const int fsw0 = ((0 * 4 + q4) ^ (r & 7)) * 8;
  const int fsw1 = ((1 * 4 + q4) ^ (r & 7)) * 8;

  for (int i = 0; i < NTh; i++) {
    // stage tiles i (slot 0) and i+NTh (slot 1), single-buffered
    gload_lds16(Ksrc + (size_t)i * (64 * HD),          &kbuf[0][w * 512]);
    gload_lds16(Vsrc + i * 64,                         &vbuf[0][w * 512]);
    gload_lds16(Ksrc + (size_t)(i + NTh) * (64 * HD),  &kbuf[1][w * 512]);
    gload_lds16(Vsrc + (i + NTh) * 64,                 &vbuf[1][w * 512]);
    __syncthreads();                    // drains vmcnt -> slots ready
    const int kt = i + hf * NTh;
    if (kt <= ktmax)
      attn_step(&kbuf[hf][0], &vbuf[hf][0], qf, of, m_run, lp, pw,
                kt, kt == ktmax, q0, r, q4, fsw0, fsw1);
    __syncthreads();                    // all reads done before next iter's writes
  }

  // ---- in-LDS merge of the two k-halves per subtile (overlaid on p_sh) ----
  float* msh = reinterpret_cast<float*>(&p_sh[0][0]);   // 4 slots x 36x64 f32
  if (hf == 1) {
    float* mb = msh + (s * 36) * 64 + lane;
    #pragma unroll
    for (int g = 0; g < 2; g++) {
      #pragma unroll
      for (int d0 = 0; d0 < 4; d0++)
        #pragma unroll
        for (int jj = 0; jj < 4; jj++)
          mb[(g * 16 + d0 * 4 + jj) * 64] = of[g][d0][jj];
      mb[(32 + g) * 64] = m_run[g];
      mb[(34 + g) * 64] = lp[g];
    }
  }
  __syncthreads();
  if (hf == 0) {
    const float* mb = msh + (s * 36) * 64 + lane;
    #pragma unroll
    for (int g = 0; g < 2; g++) {
      float m1 = mb[(32 + g) * 64];
      float l1 = mb[(34 + g) * 64];
      float M = fmaxf(m_run[g], m1);
      float a0 = __builtin_amdgcn_exp2f(m_run[g] - M);
      float a1 = __builtin_amdgcn_exp2f(m1 - M);
      float lc = lp[g] * a0 + l1 * a1;
      lc += __shfl_xor(lc, 16);
      lc += __shfl_xor(lc, 32);
      float inv = 1.0f / lc;
      const int t = q0 + g * 16 + r;
      #pragma unroll
      for (int d0 = 0; d0 < 4; d0++) {
        f32x4 oc;
        #pragma unroll
        for (int jj = 0; jj < 4; jj++)
          oc[jj] = of[g][d0][jj] * a0 + mb[(g * 16 + d0 * 4 + jj) * 64] * a1;
        bf16x4v yv;
        yv[0] = (__bf16)(oc[0] * inv); yv[1] = (__bf16)(oc[1] * inv);
        yv[2] = (__bf16)(oc[2] * inv); yv[3] = (__bf16)(oc[3] * inv);
        *reinterpret_cast<bf16x4v*>(&Y[((size_t)(b * TT + t) << 10) + h * 64 + d0 * 16 + q4 * 4]) = yv;
      }
    }
  }
}

// ---------------- host launcher ----------------
extern "C" void kernel_launch(void* const* d_in, const int* in_sizes, int n_in,
                              void* d_out, int out_size, void* d_ws, size_t ws_size,
                              hipStream_t stream) {
  const float* x     = (const float*)d_in[0];
  const float* w_qkv = (const float*)d_in[1];
  const float* b_qkv = (const float*)d_in[2];
  const float* w_out = (const float*)d_in[3];
  const float* b_out = (const float*)d_in[4];
  float* out = (float*)d_out;

  uint8_t* ws = (uint8_t*)d_ws;
  u16* xb    = (u16*)(ws);                    // 8 MB  (reused as y_heads later)
  u16* wqkvT = (u16*)(ws + (8u  << 20));      // 6 MB
  u16* woutT = (u16*)(ws + (14u << 20));      // 2 MB
  u16* Qh    = (u16*)(ws + (16u << 20));      // 8 MB
  u16* Kh    = (u16*)(ws + (24u << 20));      // 8 MB
  u16* Vth   = (u16*)(ws + (32u << 20));      // 8 MB  (transposed V)

  k_f32_to_bf16<<<1024, 256, 0, stream>>>(x, xb, (MR * D_MODEL) / 4);
  k_transpose_both<<<dim3(128, D_MODEL / 32), dim3(32, 8), 0, stream>>>(
      w_qkv, w_out, wqkvT, woutT);

  k_gemm_bt<0><<<dim3(3 * D_MODEL / 128, MR / 128), 256, 0, stream>>>(
      xb, wqkvT, b_qkv, Qh, Kh, Vth, nullptr, MR, 3 * D_MODEL, D_MODEL);

  u16* Yh = xb;  // reuse x-bf16 region
  k_attn<<<dim3(512), dim3(512), 0, stream>>>(Qh, Kh, Vth, Yh);

  k_gemm_bt<1><<<dim3(D_MODEL / 128, MR / 128), 256, 0, stream>>>(
      Yh, woutT, b_out, nullptr, nullptr, nullptr, out, MR, D_MODEL, D_MODEL);
}

// Round 21
// 114.538 us; speedup vs baseline: 1.2244x; 1.0753x over previous
//
#include <hip/hip_runtime.h>
#include <stdint.h>

#define D_MODEL 1024
#define NHEAD 16
#define HD 64
#define BB 2
#define TT 2048
#define MR (BB*TT)   // 4096 rows

#define SCL2 0.18033688011112042f   // 0.125 * log2(e), folded into Q at projection

typedef unsigned short u16;
typedef __bf16 bf16x8 __attribute__((ext_vector_type(8)));
typedef __bf16 bf16x4v __attribute__((ext_vector_type(4)));
typedef u16 u16x8 __attribute__((ext_vector_type(8)));
typedef float f32x4 __attribute__((ext_vector_type(4)));

__device__ __forceinline__ u16 f2bf(float f) {
  union { float f; unsigned u; } v; v.f = f;
  unsigned r = v.u + 0x7FFFu + ((v.u >> 16) & 1u);
  return (u16)(r >> 16);
}

__device__ __forceinline__ void gload_lds16(const void* g, void* l) {
  __builtin_amdgcn_global_load_lds(
      (const __attribute__((address_space(1))) void*)g,
      (__attribute__((address_space(3))) void*)l, 16, 0, 0);
}

// ---------------- f32 -> bf16 convert (vectorized) ----------------
__global__ void k_f32_to_bf16(const float* __restrict__ src, u16* __restrict__ dst, int n4) {
  int idx = blockIdx.x * blockDim.x + threadIdx.x;
  int stride = gridDim.x * blockDim.x;
  for (int i = idx; i < n4; i += stride) {
    float4 v = reinterpret_cast<const float4*>(src)[i];
    ushort4 o;
    o.x = f2bf(v.x); o.y = f2bf(v.y); o.z = f2bf(v.z); o.w = f2bf(v.w);
    reinterpret_cast<ushort4*>(dst)[i] = o;
  }
}

// ---------------- transpose f32 [K][N] -> bf16 [N][K], both weights fused ----------------
__global__ void k_transpose_both(const float* __restrict__ wqkv, const float* __restrict__ wout,
                                 u16* __restrict__ dqkv, u16* __restrict__ dout) {
  __shared__ float tile[32][33];
  int bx = blockIdx.x;
  const float* src; u16* dst; int N; int n0;
  if (bx < 96) { src = wqkv; dst = dqkv; N = 3 * D_MODEL; n0 = bx * 32; }
  else         { src = wout; dst = dout; N = D_MODEL;     n0 = (bx - 96) * 32; }
  const int K = D_MODEL;
  int k0 = blockIdx.y * 32;
  int tx = threadIdx.x, ty = threadIdx.y;  // block (32,8)
  #pragma unroll
  for (int i = 0; i < 32; i += 8)
    tile[ty + i][tx] = src[(size_t)(k0 + ty + i) * N + n0 + tx];
  __syncthreads();
  #pragma unroll
  for (int i = 0; i < 32; i += 8)
    dst[(size_t)(n0 + ty + i) * K + k0 + tx] = f2bf(tile[tx][ty + i]);
}

// ---------------- bf16 GEMM1, B^T input, 128x128 tile, swizzled (R20) ----------------
__global__ __launch_bounds__(256)
void k_gemm_qkv(const u16* __restrict__ A, const u16* __restrict__ Bt,
                const float* __restrict__ bias,
                u16* __restrict__ q_out, u16* __restrict__ k_out, u16* __restrict__ v_out,
                int M, int N, int K)
{
  __shared__ __align__(16) u16 a_sh[128 * 64];
  __shared__ __align__(16) u16 b_sh[128 * 64];
  const int u = threadIdx.x;
  const int lane = u & 63;
  const int w = u >> 6;
  const int wr = w >> 1, wc = w & 1;    // 2x2 wave grid, 64x64 quadrant each
  const int m0 = blockIdx.y * 128;
  const int n0 = blockIdx.x * 128;
  const int r = lane & 15, q4 = lane >> 4;

  f32x4 acc[4][4];
  #pragma unroll
  for (int i = 0; i < 4; i++)
    #pragma unroll
    for (int j = 0; j < 4; j++) acc[i][j] = {0.f, 0.f, 0.f, 0.f};

  const int arow = u >> 3;
  const int acol = ((u & 7) ^ ((u >> 3) & 7)) * 8;
  const u16* Ag = A + (size_t)(m0 + arow) * K + acol;
  const u16* Bg = Bt + (size_t)(n0 + arow) * K + acol;

  const int fs0 = ((0 * 4 + q4) ^ (r & 7)) * 8;
  const int fs1 = ((1 * 4 + q4) ^ (r & 7)) * 8;

  for (int k0 = 0; k0 < K; k0 += 64) {
    #pragma unroll
    for (int i = 0; i < 4; i++) {
      gload_lds16(Ag + (size_t)i * 32 * K + k0, &a_sh[(i * 32 + w * 8) * 64]);
      gload_lds16(Bg + (size_t)i * 32 * K + k0, &b_sh[(i * 32 + w * 8) * 64]);
    }
    __syncthreads();
    #pragma unroll
    for (int kc = 0; kc < 2; kc++) {
      const int fs = kc ? fs1 : fs0;
      bf16x8 af[4], bfr[4];
      #pragma unroll
      for (int m = 0; m < 4; m++)
        af[m] = *reinterpret_cast<const bf16x8*>(&a_sh[(wr * 64 + m * 16 + r) * 64 + fs]);
      #pragma unroll
      for (int n = 0; n < 4; n++)
        bfr[n] = *reinterpret_cast<const bf16x8*>(&b_sh[(wc * 64 + n * 16 + r) * 64 + fs]);
      #pragma unroll
      for (int m = 0; m < 4; m++)
        #pragma unroll
        for (int n = 0; n < 4; n++)
          acc[m][n] = __builtin_amdgcn_mfma_f32_16x16x32_bf16(af[m], bfr[n], acc[m][n], 0, 0, 0);
    }
    __syncthreads();
  }

  #pragma unroll
  for (int n = 0; n < 4; n++) {
    int gcol = n0 + wc * 64 + n * 16 + r;
    int which = gcol >> 10;
    int rem = gcol & 1023;
    int h = rem >> 6, d = rem & 63;
    float bv = bias[gcol];
    #pragma unroll
    for (int m = 0; m < 4; m++) {
      #pragma unroll
      for (int reg = 0; reg < 4; reg++) {
        int grow = m0 + wr * 64 + m * 16 + q4 * 4 + reg;
        int b = grow >> 11, t = grow & 2047;
        float fv = acc[m][n][reg] + bv;
        if (which == 0)
          q_out[(((size_t)(b * NHEAD + h) * TT + t) << 6) + d] = f2bf(fv * SCL2);
        else if (which == 1)
          k_out[(((size_t)(b * NHEAD + h) * TT + t) << 6) + d] = f2bf(fv);
        else  // V transposed: [b][h][d][t]
          v_out[(((size_t)(b * NHEAD + h) * HD + d) * TT) + t] = f2bf(fv);
      }
    }
  }
}

// ---------------- bf16 GEMM2, B^T input, 128x64 tile, swizzled (R17) ----------------
// 512 blocks (2/CU) -- the 128^2 shape leaves MODE1 at 256 blocks (1/CU).
__global__ __launch_bounds__(256)
void k_gemm_out(const u16* __restrict__ A, const u16* __restrict__ Bt,
                const float* __restrict__ bias, float* __restrict__ c_out,
                int M, int N, int K)
{
  __shared__ __align__(16) u16 a_sh[128 * 64];
  __shared__ __align__(16) u16 b_sh[64 * 64];
  const int u = threadIdx.x;
  const int lane = u & 63;
  const int w = u >> 6;           // wave = row quadrant (32 rows)
  const int m0 = blockIdx.y * 128;
  const int n0 = blockIdx.x * 64;
  const int r = lane & 15, q4 = lane >> 4;

  f32x4 acc[2][4];
  #pragma unroll
  for (int i = 0; i < 2; i++)
    #pragma unroll
    for (int j = 0; j < 4; j++) acc[i][j] = {0.f, 0.f, 0.f, 0.f};

  const int arow = u >> 3;
  const int acol = ((u & 7) ^ ((u >> 3) & 7)) * 8;
  const u16* Ag = A + (size_t)(m0 + arow) * K + acol;
  const u16* Bg = Bt + (size_t)(n0 + arow) * K + acol;

  const int fs0 = ((0 * 4 + q4) ^ (r & 7)) * 8;
  const int fs1 = ((1 * 4 + q4) ^ (r & 7)) * 8;

  for (int k0 = 0; k0 < K; k0 += 64) {
    #pragma unroll
    for (int i = 0; i < 4; i++)
      gload_lds16(Ag + (size_t)i * 32 * K + k0, &a_sh[(i * 32 + w * 8) * 64]);
    #pragma unroll
    for (int i = 0; i < 2; i++)
      gload_lds16(Bg + (size_t)i * 32 * K + k0, &b_sh[(i * 32 + w * 8) * 64]);
    __syncthreads();
    #pragma unroll
    for (int kc = 0; kc < 2; kc++) {
      const int fs = kc ? fs1 : fs0;
      bf16x8 af[2], bfr[4];
      #pragma unroll
      for (int m = 0; m < 2; m++)
        af[m] = *reinterpret_cast<const bf16x8*>(&a_sh[(w * 32 + m * 16 + r) * 64 + fs]);
      #pragma unroll
      for (int n = 0; n < 4; n++)
        bfr[n] = *reinterpret_cast<const bf16x8*>(&b_sh[(n * 16 + r) * 64 + fs]);
      #pragma unroll
      for (int m = 0; m < 2; m++)
        #pragma unroll
        for (int n = 0; n < 4; n++)
          acc[m][n] = __builtin_amdgcn_mfma_f32_16x16x32_bf16(af[m], bfr[n], acc[m][n], 0, 0, 0);
    }
    __syncthreads();
  }

  #pragma unroll
  for (int m = 0; m < 2; m++) {
    #pragma unroll
    for (int reg = 0; reg < 4; reg++) {
      int grow = m0 + w * 32 + m * 16 + q4 * 4 + reg;
      #pragma unroll
      for (int n = 0; n < 4; n++) {
        int gcol = n0 + n * 16 + r;
        c_out[(size_t)grow * N + gcol] = acc[m][n][reg] + bias[gcol];
      }
    }
  }
}

// ---------------- causal flash attention: 64-row blocks + backfill ----------------
// 1024 blocks of 256 (4 waves = 2 subtiles x 2 k-halves). Block = (head,
// 64-row tile s64), duration ceil((s64+1)/2) = 1..16, longest-first dispatch.
// LDS 51.2 KB -> 3 blocks/CU resident + queue backfill (R13 lever applied to
// the staged-LDS attn: short blocks refill CUs -> span ~11.4 iter-equivalents
// vs R16's 16). K/V staged ONCE per block in swizzled LDS (R19 lesson: keep
// both shared); in-LDS 2-way split-K merge. Body identical to R16-R20.
#define DEFER_THR 6.0f

__device__ __forceinline__ void attn_step(
    const u16* __restrict__ kb, const u16* __restrict__ vb,
    const bf16x8 (&qf)[2][2], f32x4 (&of)[2][4],
    float (&m_run)[2], float (&lp)[2],
    u16* pw, int kt, bool diag, int q0, int r, int q4, int fsw0, int fsw1)
{
  // S^T = mfma(K, Q): K A-fragments from swizzled LDS
  f32x4 sf[2][4];
  __builtin_amdgcn_s_setprio(1);
  #pragma unroll
  for (int n = 0; n < 4; n++) {
    bf16x8 k0f = *reinterpret_cast<const bf16x8*>(&kb[(n * 16 + r) * 64 + fsw0]);
    bf16x8 k1f = *reinterpret_cast<const bf16x8*>(&kb[(n * 16 + r) * 64 + fsw1]);
    #pragma unroll
    for (int g = 0; g < 2; g++) {
      f32x4 a = {0.f, 0.f, 0.f, 0.f};
      a = __builtin_amdgcn_mfma_f32_16x16x32_bf16(k0f, qf[g][0], a, 0, 0, 0);
      a = __builtin_amdgcn_mfma_f32_16x16x32_bf16(k1f, qf[g][1], a, 0, 0, 0);
      sf[g][n] = a;
    }
  }
  __builtin_amdgcn_s_setprio(0);

  // V A-fragments from swizzled LDS
  bf16x8 vf[2][4];
  #pragma unroll
  for (int d0 = 0; d0 < 4; d0++) {
    vf[0][d0] = *reinterpret_cast<const bf16x8*>(&vb[(d0 * 16 + r) * 64 + fsw0]);
    vf[1][d0] = *reinterpret_cast<const bf16x8*>(&vb[(d0 * 16 + r) * 64 + fsw1]);
  }

  #pragma unroll
  for (int g = 0; g < 2; g++) {
    const int myq = q0 + g * 16 + r;
    if (diag) {
      #pragma unroll
      for (int n = 0; n < 4; n++)
        #pragma unroll
        for (int reg = 0; reg < 4; reg++) {
          int kg = kt * 64 + n * 16 + q4 * 4 + reg;
          if (kg > myq) sf[g][n][reg] = -1e30f;
        }
    }
    float ma = fmaxf(fmaxf(sf[g][0][0], sf[g][0][1]), sf[g][0][2]);
    float mb = fmaxf(fmaxf(sf[g][0][3], sf[g][1][0]), sf[g][1][1]);
    float mc = fmaxf(fmaxf(sf[g][1][2], sf[g][1][3]), sf[g][2][0]);
    float md = fmaxf(fmaxf(sf[g][2][1], sf[g][2][2]), sf[g][2][3]);
    float me = fmaxf(fmaxf(sf[g][3][0], sf[g][3][1]), sf[g][3][2]);
    float mt = fmaxf(fmaxf(fmaxf(ma, mb), fmaxf(mc, md)), fmaxf(me, sf[g][3][3]));

    if (!__all(mt <= m_run[g] + DEFER_THR)) {
      float fm = fmaxf(mt, __shfl_xor(mt, 16));
      fm = fmaxf(fm, __shfl_xor(fm, 32));
      float mnew = fmaxf(m_run[g], fm);
      float alpha = __builtin_amdgcn_exp2f(m_run[g] - mnew);
      lp[g] *= alpha;
      #pragma unroll
      for (int d0 = 0; d0 < 4; d0++)
        of[g][d0] *= alpha;
      m_run[g] = mnew;
    }

    f32x4 ss = {0.f, 0.f, 0.f, 0.f};
    #pragma unroll
    for (int n = 0; n < 4; n++) {
      #pragma unroll
      for (int reg = 0; reg < 4; reg++)
        sf[g][n][reg] = __builtin_amdgcn_exp2f(sf[g][n][reg] - m_run[g]);
      ss += sf[g][n];
    }
    lp[g] += (ss[0] + ss[1]) + (ss[2] + ss[3]);

    #pragma unroll
    for (int n = 0; n < 4; n++) {
      bf16x4v pv;
      pv[0] = (__bf16)sf[g][n][0]; pv[1] = (__bf16)sf[g][n][1];
      pv[2] = (__bf16)sf[g][n][2]; pv[3] = (__bf16)sf[g][n][3];
      *reinterpret_cast<bf16x4v*>(&pw[(g * 16 + r) * 72 + n * 16 + q4 * 4]) = pv;
    }
  }

  // O^T += mfma(V, P)
  #pragma unroll
  for (int g = 0; g < 2; g++)
    #pragma unroll
    for (int kc = 0; kc < 2; kc++) {
      bf16x8 pa = *reinterpret_cast<const bf16x8*>(&pw[(g * 16 + r) * 72 + kc * 32 + q4 * 8]);
      #pragma unroll
      for (int d0 = 0; d0 < 4; d0++)
        of[g][d0] = __builtin_amdgcn_mfma_f32_16x16x32_bf16(vf[kc][d0], pa, of[g][d0], 0, 0, 0);
    }
}

__global__ __launch_bounds__(256)
void k_attn(const u16* __restrict__ Q, const u16* __restrict__ Kk,
            const u16* __restrict__ Vt, u16* __restrict__ Y)
{
  __shared__ __align__(16) u16 kbuf[2][64 * 64];   // 16 KB (2 k-half slots)
  __shared__ __align__(16) u16 vbuf[2][64 * 64];   // 16 KB
  __shared__ __align__(16) u16 p_sh[4][32 * 72];   // 18432 B; overlaid by merge (2 x 36x64 f32)

  const int u = threadIdx.x;
  const int lane = u & 63;
  const int w = u >> 6;                 // 0..3
  const int r = lane & 15, q4 = lane >> 4;
  const int xcd = blockIdx.x & 7;
  const int j = blockIdx.x >> 3;        // 0..127
  const int bh = xcd * 4 + (j & 3);     // head 0..31, resident per XCD
  const int s64 = 31 - (j >> 2);        // 64-row tile, longest-first
  const int s = w & 1;                  // subtile (32 rows)
  const int hf = w >> 1;                // k-half
  const int b = bh >> 4, h = bh & 15;
  const size_t head_off = (size_t)bh * TT * HD;   // Q,K: [t][d]; Vt: [d][t]
  const int q0 = s64 * 64 + s * 32;     // this wave's 32 q-rows
  const int NT = s64 + 1;               // total k-tiles
  const int NTh = (NT + 1) >> 1;        // iterations (half, rounded up)
  const int ktmax = s64;

  // staging: wave w stages rows [w*16, w*16+16) of each slot's tile (2 gloads each)
  const int srow = w * 16 + (lane >> 3);
  const int sg = (lane & 7) ^ (srow & 7);     // (srow+8)&7 == srow&7, so sg shared
  const u16* Ksrc = Kk + head_off + (size_t)srow * HD + sg * 8;
  const u16* Vsrc = Vt + head_off + (size_t)srow * TT + sg * 8;

  bf16x8 qf[2][2];
  #pragma unroll
  for (int g = 0; g < 2; g++) {
    const u16* qp = &Q[head_off + (size_t)(q0 + g * 16 + r) * HD + q4 * 8];
    qf[g][0] = *reinterpret_cast<const bf16x8*>(qp);
    qf[g][1] = *reinterpret_cast<const bf16x8*>(qp + 32);
  }

  f32x4 of[2][4];
  #pragma unroll
  for (int g = 0; g < 2; g++)
    #pragma unroll
    for (int k = 0; k < 4; k++) of[g][k] = {0.f, 0.f, 0.f, 0.f};
  float m_run[2] = {-1e30f, -1e30f};
  float lp[2] = {0.f, 0.f};

  u16* pw = &p_sh[w][0];
  const int fsw0 = ((0 * 4 + q4) ^ (r & 7)) * 8;
  const int fsw1 = ((1 * 4 + q4) ^ (r & 7)) * 8;

  for (int i = 0; i < NTh; i++) {
    const int t1 = NTh + i;             // slot-1 tile (t1 <= NT <= 32, rows < 2048: safe)
    gload_lds16(Ksrc + (size_t)i  * (64 * HD),          &kbuf[0][(w * 16) * 64]);
    gload_lds16(Ksrc + (size_t)i  * (64 * HD) + 8 * HD, &kbuf[0][(w * 16 + 8) * 64]);
    gload_lds16(Ksrc + (size_t)t1 * (64 * HD),          &kbuf[1][(w * 16) * 64]);
    gload_lds16(Ksrc + (size_t)t1 * (64 * HD) + 8 * HD, &kbuf[1][(w * 16 + 8) * 64]);
    gload_lds16(Vsrc + i * 64,                          &vbuf[0][(w * 16) * 64]);
    gload_lds16(Vsrc + i * 64 + 8 * TT,                 &vbuf[0][(w * 16 + 8) * 64]);
    gload_lds16(Vsrc + t1 * 64,                         &vbuf[1][(w * 16) * 64]);
    gload_lds16(Vsrc + t1 * 64 + 8 * TT,                &vbuf[1][(w * 16 + 8) * 64]);
    __syncthreads();                    // drains vmcnt -> slots ready
    const int kt = i + hf * NTh;
    if (kt < NT)
      attn_step(&kbuf[hf][0], &vbuf[hf][0], qf, of, m_run, lp, pw,
                kt, kt == ktmax, q0, r, q4, fsw0, fsw1);
    __syncthreads();                    // all reads done before next iter's writes
  }

  // ---- in-LDS merge of the two k-halves per subtile (overlaid on p_sh) ----
  float* msh = reinterpret_cast<float*>(&p_sh[0][0]);   // 2 slots x 36x64 f32
  if (hf == 1) {
    float* mb = msh + (s * 36) * 64 + lane;
    #pragma unroll
    for (int g = 0; g < 2; g++) {
      #pragma unroll
      for (int d0 = 0; d0 < 4; d0++)
        #pragma unroll
        for (int jj = 0; jj < 4; jj++)
          mb[(g * 16 + d0 * 4 + jj) * 64] = of[g][d0][jj];
      mb[(32 + g) * 64] = m_run[g];
      mb[(34 + g) * 64] = lp[g];
    }
  }
  __syncthreads();
  if (hf == 0) {
    const float* mb = msh + (s * 36) * 64 + lane;
    #pragma unroll
    for (int g = 0; g < 2; g++) {
      float m1 = mb[(32 + g) * 64];
      float l1 = mb[(34 + g) * 64];
      float M = fmaxf(m_run[g], m1);
      float a0 = __builtin_amdgcn_exp2f(m_run[g] - M);
      float a1 = __builtin_amdgcn_exp2f(m1 - M);
      float lc = lp[g] * a0 + l1 * a1;
      lc += __shfl_xor(lc, 16);
      lc += __shfl_xor(lc, 32);
      float inv = 1.0f / lc;
      const int t = q0 + g * 16 + r;
      #pragma unroll
      for (int d0 = 0; d0 < 4; d0++) {
        f32x4 oc;
        #pragma unroll
        for (int jj = 0; jj < 4; jj++)
          oc[jj] = of[g][d0][jj] * a0 + mb[(g * 16 + d0 * 4 + jj) * 64] * a1;
        bf16x4v yv;
        yv[0] = (__bf16)(oc[0] * inv); yv[1] = (__bf16)(oc[1] * inv);
        yv[2] = (__bf16)(oc[2] * inv); yv[3] = (__bf16)(oc[3] * inv);
        *reinterpret_cast<bf16x4v*>(&Y[((size_t)(b * TT + t) << 10) + h * 64 + d0 * 16 + q4 * 4]) = yv;
      }
    }
  }
}

// ---------------- host launcher ----------------
extern "C" void kernel_launch(void* const* d_in, const int* in_sizes, int n_in,
                              void* d_out, int out_size, void* d_ws, size_t ws_size,
                              hipStream_t stream) {
  const float* x     = (const float*)d_in[0];
  const float* w_qkv = (const float*)d_in[1];
  const float* b_qkv = (const float*)d_in[2];
  const float* w_out = (const float*)d_in[3];
  const float* b_out = (const float*)d_in[4];
  float* out = (float*)d_out;

  uint8_t* ws = (uint8_t*)d_ws;
  u16* xb    = (u16*)(ws);                    // 8 MB  (reused as y_heads later)
  u16* wqkvT = (u16*)(ws + (8u  << 20));      // 6 MB
  u16* woutT = (u16*)(ws + (14u << 20));      // 2 MB
  u16* Qh    = (u16*)(ws + (16u << 20));      // 8 MB
  u16* Kh    = (u16*)(ws + (24u << 20));      // 8 MB
  u16* Vth   = (u16*)(ws + (32u << 20));      // 8 MB  (transposed V)

  k_f32_to_bf16<<<1024, 256, 0, stream>>>(x, xb, (MR * D_MODEL) / 4);
  k_transpose_both<<<dim3(128, D_MODEL / 32), dim3(32, 8), 0, stream>>>(
      w_qkv, w_out, wqkvT, woutT);

  k_gemm_qkv<<<dim3(3 * D_MODEL / 128, MR / 128), 256, 0, stream>>>(
      xb, wqkvT, b_qkv, Qh, Kh, Vth, MR, 3 * D_MODEL, D_MODEL);

  u16* Yh = xb;  // reuse x-bf16 region
  k_attn<<<dim3(1024), dim3(256), 0, stream>>>(Qh, Kh, Vth, Yh);

  k_gemm_out<<<dim3(D_MODEL / 64, MR / 128), 256, 0, stream>>>(
      Yh, woutT, b_out, out, MR, D_MODEL, D_MODEL);
}